// Round 6
// baseline (285.562 us; speedup 1.0000x reference)
//
#include <hip/hip_runtime.h>
#include <hip/hip_bf16.h>

// Problem constants
#define CO    128
#define CI    128
#define NPIX  3136   // 56*56
#define PH    58
#define PPIX  3364   // 58*58
#define HPX8  100    // halo pixels per 8x8 tile: 10 x 10
#define SROW2 144    // LDS bytes per halo pixel per ci-half: 128 data + 16 pad

typedef __bf16 bf16x8 __attribute__((ext_vector_type(8)));
typedef float  f32x4  __attribute__((ext_vector_type(4)));

// ---------------------------------------------------------------------------
// Fused prep: [0,2048) weights | [2048,2504) border zero | [2504,4072) transpose.
// it layout: [b][ci-half h][3364 px][64 ci].  (unchanged)
// ---------------------------------------------------------------------------
__global__ void prep_all(const float* __restrict__ in,
                         const float* __restrict__ eps,
                         const float* __restrict__ psi,
                         const float* __restrict__ mu,
                         __bf16* __restrict__ wt,
                         __bf16* __restrict__ it) {
  __shared__ __align__(16) char smem[32256];
  const int bx = blockIdx.x, tid = threadIdx.x;

  if (bx < 2048) {
    // ---- weights phase: block covers idx0..idx0+255 (one b, two co) ----
    float* Ebuf = (float*)smem;              // 2304 f32
    float* Pbuf = (float*)(smem + 9216);     // 2304 f32
    float* Mbuf = (float*)(smem + 18432);    // 2304 f32
    __bf16* Wb  = (__bf16*)(smem + 27648);   // [9][256] bf16
    const int idx0  = bx * 256;              // multiple of 256 -> ci0 = 0
    const int b     = idx0 >> 14;            // 64 blocks per b, no straddle
    const int coci0 = idx0 & 16383;          // co0*CI
    const f32x4* esrc = (const f32x4*)(eps + (size_t)idx0 * 9);
    const f32x4* psrc = (const f32x4*)(psi + (size_t)coci0 * 9);
    const f32x4* msrc = (const f32x4*)(mu  + (size_t)coci0 * 9);
#pragma unroll
    for (int i = 0; i < 3; ++i) {            // 576 f32x4 per array
      int j = i * 256 + tid;
      if (j < 576) {
        ((f32x4*)Ebuf)[j] = esrc[j];
        ((f32x4*)Pbuf)[j] = psrc[j];
        ((f32x4*)Mbuf)[j] = msrc[j];
      }
    }
    __syncthreads();
#pragma unroll
    for (int p = 0; p < 9; ++p) {
      float v = Ebuf[tid * 9 + p] * __expf(Pbuf[tid * 9 + p]) + Mbuf[tid * 9 + p];
      Wb[p * 256 + tid] = (__bf16)v;
    }
    __syncthreads();
    __bf16* wb = wt + (size_t)b * 9 * CO * CI + coci0;
#pragma unroll
    for (int i = 0; i < 2; ++i) {
      int s = i * 256 + tid;
      if (s < 288) {
        int p = s >> 5, j = s & 31;
        *(f32x4*)(wb + (size_t)p * CO * CI + j * 8) =
            *(const f32x4*)&Wb[p * 256 + j * 8];
      }
    }
  } else if (bx < 2504) {
    int cid = (bx - 2048) * 256 + tid;
    int pid = cid >> 4;
    int chunk = cid & 15;                    // 16 chunks of 16B per pixel
    int h  = chunk >> 3;                     // ci-half
    int c8 = chunk & 7;
    int b = pid / 228;
    int e = pid - b * 228;
    int ph, pw;
    if (e < 58)       { ph = 0;       pw = e; }
    else if (e < 116) { ph = 57;      pw = e - 58; }
    else if (e < 172) { ph = e - 115; pw = 0; }
    else              { ph = e - 171; pw = 57; }
    f32x4 z = {0.f, 0.f, 0.f, 0.f};
    *(f32x4*)&it[((size_t)(b * 2 + h) * PPIX + ph * PH + pw) * 64 + c8 * 8] = z;
  } else {
    __bf16 (*T)[136] = (__bf16(*)[136])smem;   // [64][136]
    int tx = bx - 2504;
    int b  = tx / 49;
    int p0 = (tx - b * 49) * 64;
    const float* src = in + (size_t)b * CI * NPIX;
#pragma unroll
    for (int jj = 0; jj < 8; ++jj) {
      int c = jj * 256 + tid;
      int ci = c >> 4, xc = c & 15;
      float4 v = *(const float4*)(src + (size_t)ci * NPIX + p0 + xc * 4);
      T[xc * 4 + 0][ci] = (__bf16)v.x;
      T[xc * 4 + 1][ci] = (__bf16)v.y;
      T[xc * 4 + 2][ci] = (__bf16)v.z;
      T[xc * 4 + 3][ci] = (__bf16)v.w;
    }
    __syncthreads();
#pragma unroll
    for (int jj = 0; jj < 4; ++jj) {
      int c = jj * 256 + tid;
      int pl = c >> 4, xc = c & 15;
      int h  = xc >> 3;
      int c8 = xc & 7;
      int pix = p0 + pl;
      int oh = pix / 56, ow = pix - oh * 56;
      int ppix = (oh + 1) * PH + (ow + 1);
      *(f32x4*)&it[((size_t)(b * 2 + h) * PPIX + ppix) * 64 + c8 * 8] =
          *(const f32x4*)&T[pl][xc * 8];
    }
  }
}

// ---------------------------------------------------------------------------
// GEMM/conv, 8x8-pixel tiles for max residency:
//   block = 128 co x 64 n (8x8 output pixels), 4 waves of 32co x 64n
//   (2 m-frags x 4 n-frags, acc = 32 VGPR).  Halo per ci-half: 10x10 px x
//   144B = 14.4KB LDS -> 8+ blocks/CU -> 32 waves/CU (2x round-4; LDS was
//   the residency cap in every prior config).  K-loop = 2 halves x 18 steps
//   (tap x 32ci), restage at midpoint (2 barriers).  A: global->VGPR
//   distance-2 ring; setprio around MFMA cluster.  Grid 49 tiles x 32 b =
//   1568 blocks (~6.1/CU, balanced).
// ---------------------------------------------------------------------------
__global__ __launch_bounds__(256, 8) void bconv_gemm(
    const __bf16* __restrict__ wt,   // [b][9][128 co][128 ci]
    const __bf16* __restrict__ it,   // [b][2 h][3364 px][64 ci]
    float* __restrict__ out) {       // [b][128 co][3136 n]
  __shared__ __align__(16) char Bsh[HPX8 * SROW2];   // 14400 B
  const int tid  = threadIdx.x;
  const int w    = tid >> 6;
  const int lane = tid & 63;
  const int quad = lane >> 4;
  const int l15  = lane & 15;

  // Decode: lin = x + 8*(t*4 + bhi); b = x + 8*bhi -> same-b blocks share an XCD
  const int lin = blockIdx.x;
  const int x   = lin & 7;
  const int j   = lin >> 3;          // 0..195
  const int bhi = j & 3;
  const int t   = j >> 2;            // 0..48
  const int b   = x + 8 * bhi;
  const int th  = t / 7;             // tile row 0..6
  const int tw  = t - th * 7;        // tile col 0..6

  // ---- halo staging, ci-half 0: 100 px x 8 chunks of 16B = 800 chunks ----
  const __bf16* hsrc0 = it + ((size_t)(b * 2 + 0) * PPIX + (th * 8) * PH + tw * 8) * 64;
  const __bf16* hsrc1 = it + ((size_t)(b * 2 + 1) * PPIX + (th * 8) * PH + tw * 8) * 64;
#pragma unroll
  for (int i = 0; i < 4; ++i) {
    int idx = i * 256 + tid;
    if (idx < HPX8 * 8) {
      int px = idx >> 3, sub = idx & 7;
      int r = px / 10, c = px - r * 10;
      *(f32x4*)&Bsh[px * SROW2 + sub * 16] =
          *(const f32x4*)(hsrc0 + ((size_t)r * PH + c) * 64 + sub * 8);
    }
  }
  __syncthreads();

  // ---- per-lane B fragment LDS byte-bases (tap (0,0), kk=0) ----
  // frag nf covers output pixels rows [nf*2, nf*2+2) x cols [0,8):
  //   n-lane l15 -> orow = nf*2 + (l15>>3), ocol = l15&7
  int bbase[4];
#pragma unroll
  for (int nf = 0; nf < 4; ++nf) {
    int orow = nf * 2 + (l15 >> 3);
    int ocol = l15 & 7;
    bbase[nf] = (orow * 10 + ocol) * SROW2 + quad * 16;
  }

  // ---- per-lane A global bases (elements) ----
  const int co0 = w * 32;
  const __bf16* wtb = wt + (size_t)b * 9 * CO * CI;
  const int ab0 = (co0 +      l15) * CI + quad * 8;
  const int ab1 = (co0 + 16 + l15) * CI + quad * 8;

  f32x4 acc[2][4] = {};
  // distance-2 A-prefetch ring (statically indexed under full unroll)
  // step t: h = t/18, s2 = t%18, p = s2>>1, kk = s2&1; A off = p*CO*CI + h*64 + kk*32
  bf16x8 areg[3][2];
  areg[0][0] = *(const bf16x8*)(wtb + ab0);
  areg[0][1] = *(const bf16x8*)(wtb + ab1);
  areg[1][0] = *(const bf16x8*)(wtb + 32 + ab0);
  areg[1][1] = *(const bf16x8*)(wtb + 32 + ab1);

#pragma unroll
  for (int s = 0; s < 36; ++s) {
    if (s == 18) {
      __syncthreads();                       // all waves done reading half 0
#pragma unroll
      for (int i = 0; i < 4; ++i) {
        int idx = i * 256 + tid;
        if (idx < HPX8 * 8) {
          int px = idx >> 3, sub = idx & 7;
          int r = px / 10, c = px - r * 10;
          *(f32x4*)&Bsh[px * SROW2 + sub * 16] =
              *(const f32x4*)(hsrc1 + ((size_t)r * PH + c) * 64 + sub * 8);
        }
      }
      __syncthreads();
    }
    // prefetch A for step s+2
    if (s < 34) {
      const int tn  = s + 2;
      const int hn  = tn / 18;
      const int s2n = tn % 18;
      const int pn  = s2n >> 1;
      const int kkn = s2n & 1;
      const __bf16* ap = wtb + pn * (CO * CI) + hn * 64 + kkn * 32;
      areg[tn % 3][0] = *(const bf16x8*)(ap + ab0);
      areg[tn % 3][1] = *(const bf16x8*)(ap + ab1);
    }
    const int s2 = s % 18;
    const int p  = s2 >> 1;
    const int kk = s2 & 1;
    const int kh = p / 3, kw = p - kh * 3;
    const int tapb = (kh * 10 + kw) * SROW2 + kk * 64;   // compile-time (unrolled)
    __builtin_amdgcn_s_setprio(1);
#pragma unroll
    for (int nf = 0; nf < 4; ++nf) {
      bf16x8 bfr = *(const bf16x8*)&Bsh[bbase[nf] + tapb];
      acc[0][nf] = __builtin_amdgcn_mfma_f32_16x16x32_bf16(areg[s % 3][0], bfr, acc[0][nf], 0, 0, 0);
      acc[1][nf] = __builtin_amdgcn_mfma_f32_16x16x32_bf16(areg[s % 3][1], bfr, acc[1][nf], 0, 0, 0);
    }
    __builtin_amdgcn_s_setprio(0);
  }

  // ---- epilogue: C col(l15)=n, row(quad*4+r)=co ----
  float* ob = out + (size_t)b * CO * NPIX + (th * 8) * 56 + tw * 8;
#pragma unroll
  for (int mf = 0; mf < 2; ++mf) {
#pragma unroll
    for (int nf = 0; nf < 4; ++nf) {
      int orow = nf * 2 + (l15 >> 3);
      int ocol = l15 & 7;
#pragma unroll
      for (int r = 0; r < 4; ++r) {
        int co = co0 + mf * 16 + quad * 4 + r;
        ob[(size_t)co * NPIX + orow * 56 + ocol] = acc[mf][nf][r];
      }
    }
  }
}

// ---------------------------------------------------------------------------
extern "C" void kernel_launch(void* const* d_in, const int* in_sizes, int n_in,
                              void* d_out, int out_size, void* d_ws, size_t ws_size,
                              hipStream_t stream) {
  const float* inp = (const float*)d_in[0];   // [32,128,56,56]
  const float* eps = (const float*)d_in[1];   // [32,128,128,3,3]
  const float* psi = (const float*)d_in[2];   // [128,128,3,3]
  const float* mu  = (const float*)d_in[3];   // [128,128,3,3]

  // ws layout: wt (9,437,184 B) | it (27,557,888 B)
  __bf16* wt = (__bf16*)d_ws;
  __bf16* it = (__bf16*)((char*)d_ws + 9437184);

  prep_all<<<4072, 256, 0, stream>>>(inp, eps, psi, mu, wt, it);
  bconv_gemm<<<1568, 256, 0, stream>>>(wt, it, (float*)d_out);
}

// Round 7
// 181.263 us; speedup vs baseline: 1.5754x; 1.5754x over previous
//
#include <hip/hip_runtime.h>
#include <hip/hip_bf16.h>

// Problem constants
#define CO    128
#define CI    128
#define NPIX  3136   // 56*56
#define PH    58
#define PPIX  3364   // 58*58
#define HPX8  100    // halo pixels per 8x8 tile: 10 x 10
#define SROW  272    // LDS bytes per halo pixel: 256 data + 16 pad (bank balance)

typedef __bf16 bf16x8 __attribute__((ext_vector_type(8)));
typedef float  f32x4  __attribute__((ext_vector_type(4)));

// ---------------------------------------------------------------------------
// Fused prep: [0,2048) weights | [2048,2504) border zero | [2504,4072) transpose.
// it layout: [b][3364 px][128 ci]  (flat full-ci — round-2 proven version).
// ---------------------------------------------------------------------------
__global__ void prep_all(const float* __restrict__ in,
                         const float* __restrict__ eps,
                         const float* __restrict__ psi,
                         const float* __restrict__ mu,
                         __bf16* __restrict__ wt,
                         __bf16* __restrict__ it) {
  __shared__ __align__(16) char smem[32256];
  const int bx = blockIdx.x, tid = threadIdx.x;

  if (bx < 2048) {
    // ---- weights phase: block covers idx0..idx0+255 (one b, two co) ----
    float* Ebuf = (float*)smem;              // 2304 f32
    float* Pbuf = (float*)(smem + 9216);     // 2304 f32
    float* Mbuf = (float*)(smem + 18432);    // 2304 f32
    __bf16* Wb  = (__bf16*)(smem + 27648);   // [9][256] bf16
    const int idx0  = bx * 256;              // multiple of 256 -> ci0 = 0
    const int b     = idx0 >> 14;            // 64 blocks per b, no straddle
    const int coci0 = idx0 & 16383;          // co0*CI
    const f32x4* esrc = (const f32x4*)(eps + (size_t)idx0 * 9);
    const f32x4* psrc = (const f32x4*)(psi + (size_t)coci0 * 9);
    const f32x4* msrc = (const f32x4*)(mu  + (size_t)coci0 * 9);
#pragma unroll
    for (int i = 0; i < 3; ++i) {            // 576 f32x4 per array
      int j = i * 256 + tid;
      if (j < 576) {
        ((f32x4*)Ebuf)[j] = esrc[j];
        ((f32x4*)Pbuf)[j] = psrc[j];
        ((f32x4*)Mbuf)[j] = msrc[j];
      }
    }
    __syncthreads();
#pragma unroll
    for (int p = 0; p < 9; ++p) {
      float v = Ebuf[tid * 9 + p] * __expf(Pbuf[tid * 9 + p]) + Mbuf[tid * 9 + p];
      Wb[p * 256 + tid] = (__bf16)v;
    }
    __syncthreads();
    __bf16* wb = wt + (size_t)b * 9 * CO * CI + coci0;
#pragma unroll
    for (int i = 0; i < 2; ++i) {
      int s = i * 256 + tid;
      if (s < 288) {
        int p = s >> 5, j = s & 31;
        *(f32x4*)(wb + (size_t)p * CO * CI + j * 8) =
            *(const f32x4*)&Wb[p * 256 + j * 8];
      }
    }
  } else if (bx < 2504) {
    int cid = (bx - 2048) * 256 + tid;
    int pid = cid >> 4;
    int chunk = cid & 15;
    int b = pid / 228;
    int e = pid - b * 228;
    int ph, pw;
    if (e < 58)       { ph = 0;       pw = e; }
    else if (e < 116) { ph = 57;      pw = e - 58; }
    else if (e < 172) { ph = e - 115; pw = 0; }
    else              { ph = e - 171; pw = 57; }
    f32x4 z = {0.f, 0.f, 0.f, 0.f};
    *(f32x4*)&it[((size_t)b * PPIX + ph * PH + pw) * CI + chunk * 8] = z;
  } else {
    __bf16 (*T)[136] = (__bf16(*)[136])smem;   // [64][136]
    int tx = bx - 2504;
    int b  = tx / 49;
    int p0 = (tx - b * 49) * 64;
    const float* src = in + (size_t)b * CI * NPIX;
#pragma unroll
    for (int jj = 0; jj < 8; ++jj) {
      int c = jj * 256 + tid;
      int ci = c >> 4, xc = c & 15;
      float4 v = *(const float4*)(src + (size_t)ci * NPIX + p0 + xc * 4);
      T[xc * 4 + 0][ci] = (__bf16)v.x;
      T[xc * 4 + 1][ci] = (__bf16)v.y;
      T[xc * 4 + 2][ci] = (__bf16)v.z;
      T[xc * 4 + 3][ci] = (__bf16)v.w;
    }
    __syncthreads();
    __bf16* dstb = it + (size_t)b * PPIX * CI;
#pragma unroll
    for (int jj = 0; jj < 4; ++jj) {
      int c = jj * 256 + tid;
      int pl = c >> 4, xc = c & 15;
      int pix = p0 + pl;
      int oh = pix / 56, ow = pix - oh * 56;
      int ppix = (oh + 1) * PH + (ow + 1);
      *(f32x4*)&dstb[(size_t)ppix * CI + xc * 8] = *(const f32x4*)&T[pl][xc * 8];
    }
  }
}

// ---------------------------------------------------------------------------
// GEMM/conv, 8x8-pixel tiles, full-ci halo, explicit A+B register pipelines:
//   block = 128 co x 64 n (8x8 output pixels), 4 waves of 32co x 64n
//   (2 m-frags x 4 n-frags, acc = 32 AGPR).  Full-128ci halo: 10x10 px x
//   272B = 27.2KB LDS -> with launch_bounds(256,5): 5 blocks/CU = 20
//   waves/CU and NO ci-split -> single staging, ONE barrier total, zero
//   in-loop barriers.  K-loop = 9 taps x 4 ci-chunks = 36 steps.
//   A: global->VGPR distance-1 ring (2 slots).  B: explicit LDS->VGPR
//   double-buffer (load step s+1's 4 frags while step s's 8 MFMAs run) —
//   removes ds_read latency from the per-step critical path.
//   Register budget: 32 AGPR + ~66 arch ~= 98 <= 102 (512/5) -> no spills
//   (round-6 failure mode was launch_bounds(256,8)'s 64-reg cap).
//   Grid 49 tiles x 32 b = 1568 blocks (~6.1/CU).
// ---------------------------------------------------------------------------
__global__ __launch_bounds__(256, 5) void bconv_gemm(
    const __bf16* __restrict__ wt,   // [b][9][128 co][128 ci]
    const __bf16* __restrict__ it,   // [b][3364 px][128 ci]
    float* __restrict__ out) {       // [b][128 co][3136 n]
  __shared__ __align__(16) char Bsh[HPX8 * SROW];   // 27200 B
  const int tid  = threadIdx.x;
  const int w    = tid >> 6;
  const int lane = tid & 63;
  const int quad = lane >> 4;
  const int l15  = lane & 15;

  // Decode: lin = x + 8*(t*4 + bhi); b = x + 8*bhi -> same-b blocks share an XCD
  const int lin = blockIdx.x;
  const int x   = lin & 7;
  const int j   = lin >> 3;          // 0..195
  const int bhi = j & 3;
  const int t   = j >> 2;            // 0..48
  const int b   = x + 8 * bhi;
  const int th  = t / 7;             // tile row 0..6
  const int tw  = t - th * 7;        // tile col 0..6

  // ---- halo staging (full 128 ci): 100 px x 16 chunks of 16B = 1600 ----
  const __bf16* hsrc = it + ((size_t)b * PPIX + (th * 8) * PH + tw * 8) * CI;
#pragma unroll
  for (int i = 0; i < 7; ++i) {
    int idx = i * 256 + tid;
    if (idx < HPX8 * 16) {
      int px = idx >> 4, sub = idx & 15;
      int r = px / 10, c = px - r * 10;
      *(f32x4*)&Bsh[px * SROW + sub * 16] =
          *(const f32x4*)(hsrc + ((size_t)r * PH + c) * CI + sub * 8);
    }
  }
  __syncthreads();

  // ---- per-lane B fragment LDS byte-bases (tap (0,0), kk=0) ----
  // frag nf covers output rows [nf*2, nf*2+2) x cols [0,8):
  //   n-lane l15 -> orow = nf*2 + (l15>>3), ocol = l15&7
  int bbase[4];
#pragma unroll
  for (int nf = 0; nf < 4; ++nf) {
    int orow = nf * 2 + (l15 >> 3);
    int ocol = l15 & 7;
    bbase[nf] = (orow * 10 + ocol) * SROW + quad * 16;
  }

  // ---- per-lane A global bases (elements) ----
  const int co0 = w * 32;
  const __bf16* wtb = wt + (size_t)b * 9 * CO * CI;
  const int ab0 = (co0 +      l15) * CI + quad * 8;
  const int ab1 = (co0 + 16 + l15) * CI + quad * 8;

  f32x4 acc[2][4] = {};
  // step s: p = s>>2 (tap), kk = s&3 (32-ci chunk)
  // A off = p*CO*CI + kk*32 ; B LDS off = (kh*10+kw)*SROW + kk*64
  bf16x8 areg[2][2];                 // distance-1 A ring
  bf16x8 breg[2][4];                 // explicit B double-buffer
  areg[0][0] = *(const bf16x8*)(wtb + ab0);
  areg[0][1] = *(const bf16x8*)(wtb + ab1);
#pragma unroll
  for (int nf = 0; nf < 4; ++nf)
    breg[0][nf] = *(const bf16x8*)&Bsh[bbase[nf]];

#pragma unroll
  for (int s = 0; s < 36; ++s) {
    // prefetch A and B for step s+1 into the other slot
    if (s < 35) {
      const int sn  = s + 1;
      const int pn  = sn >> 2;
      const int kkn = sn & 3;
      const __bf16* ap = wtb + pn * (CO * CI) + kkn * 32;
      areg[sn & 1][0] = *(const bf16x8*)(ap + ab0);
      areg[sn & 1][1] = *(const bf16x8*)(ap + ab1);
      const int khn = pn / 3, kwn = pn - khn * 3;
      const int tapbn = (khn * 10 + kwn) * SROW + kkn * 64;   // compile-time
#pragma unroll
      for (int nf = 0; nf < 4; ++nf)
        breg[sn & 1][nf] = *(const bf16x8*)&Bsh[bbase[nf] + tapbn];
    }
    __builtin_amdgcn_s_setprio(1);
#pragma unroll
    for (int nf = 0; nf < 4; ++nf) {
      acc[0][nf] = __builtin_amdgcn_mfma_f32_16x16x32_bf16(areg[s & 1][0], breg[s & 1][nf], acc[0][nf], 0, 0, 0);
      acc[1][nf] = __builtin_amdgcn_mfma_f32_16x16x32_bf16(areg[s & 1][1], breg[s & 1][nf], acc[1][nf], 0, 0, 0);
    }
    __builtin_amdgcn_s_setprio(0);
  }

  // ---- epilogue: C col(l15)=n, row(quad*4+r)=co ----
  float* ob = out + (size_t)b * CO * NPIX + (th * 8) * 56 + tw * 8;
#pragma unroll
  for (int mf = 0; mf < 2; ++mf) {
#pragma unroll
    for (int nf = 0; nf < 4; ++nf) {
      int orow = nf * 2 + (l15 >> 3);
      int ocol = l15 & 7;
#pragma unroll
      for (int r = 0; r < 4; ++r) {
        int co = co0 + mf * 16 + quad * 4 + r;
        ob[(size_t)co * NPIX + orow * 56 + ocol] = acc[mf][nf][r];
      }
    }
  }
}

// ---------------------------------------------------------------------------
extern "C" void kernel_launch(void* const* d_in, const int* in_sizes, int n_in,
                              void* d_out, int out_size, void* d_ws, size_t ws_size,
                              hipStream_t stream) {
  const float* inp = (const float*)d_in[0];   // [32,128,56,56]
  const float* eps = (const float*)d_in[1];   // [32,128,128,3,3]
  const float* psi = (const float*)d_in[2];   // [128,128,3,3]
  const float* mu  = (const float*)d_in[3];   // [128,128,3,3]

  // ws layout: wt (9,437,184 B) | it (27,557,888 B)
  __bf16* wt = (__bf16*)d_ws;
  __bf16* it = (__bf16*)((char*)d_ws + 9437184);

  prep_all<<<4072, 256, 0, stream>>>(inp, eps, psi, mu, wt, it);
  bconv_gemm<<<1568, 256, 0, stream>>>(wt, it, (float*)d_out);
}

// Round 8
// 148.868 us; speedup vs baseline: 1.9182x; 1.2176x over previous
//
#include <hip/hip_runtime.h>
#include <hip/hip_bf16.h>

// Problem constants
#define CO    128
#define CI    128
#define NPIX  3136   // 56*56
#define PH    58
#define PPIX  3364   // 58*58
#define HPX4  348    // halo pixels per 4-row tile: 6 padded rows * 58
#define SROW2 144    // LDS bytes per halo pixel per ci-half: 128 data + 16 pad

typedef __bf16 bf16x8 __attribute__((ext_vector_type(8)));
typedef float  f32x4  __attribute__((ext_vector_type(4)));
typedef float  f32x16 __attribute__((ext_vector_type(16)));

// ---------------------------------------------------------------------------
// Fused prep: [0,2048) weights | [2048,2504) border zero | [2504,4072) transpose.
// it layout: [b][ci-half h][3364 px][64 ci]  (round 3-5 proven version).
// ---------------------------------------------------------------------------
__global__ void prep_all(const float* __restrict__ in,
                         const float* __restrict__ eps,
                         const float* __restrict__ psi,
                         const float* __restrict__ mu,
                         __bf16* __restrict__ wt,
                         __bf16* __restrict__ it) {
  __shared__ __align__(16) char smem[32256];
  const int bx = blockIdx.x, tid = threadIdx.x;

  if (bx < 2048) {
    // ---- weights phase: block covers idx0..idx0+255 (one b, two co) ----
    float* Ebuf = (float*)smem;              // 2304 f32
    float* Pbuf = (float*)(smem + 9216);     // 2304 f32
    float* Mbuf = (float*)(smem + 18432);    // 2304 f32
    __bf16* Wb  = (__bf16*)(smem + 27648);   // [9][256] bf16
    const int idx0  = bx * 256;              // multiple of 256 -> ci0 = 0
    const int b     = idx0 >> 14;            // 64 blocks per b, no straddle
    const int coci0 = idx0 & 16383;          // co0*CI
    const f32x4* esrc = (const f32x4*)(eps + (size_t)idx0 * 9);
    const f32x4* psrc = (const f32x4*)(psi + (size_t)coci0 * 9);
    const f32x4* msrc = (const f32x4*)(mu  + (size_t)coci0 * 9);
#pragma unroll
    for (int i = 0; i < 3; ++i) {            // 576 f32x4 per array
      int j = i * 256 + tid;
      if (j < 576) {
        ((f32x4*)Ebuf)[j] = esrc[j];
        ((f32x4*)Pbuf)[j] = psrc[j];
        ((f32x4*)Mbuf)[j] = msrc[j];
      }
    }
    __syncthreads();
#pragma unroll
    for (int p = 0; p < 9; ++p) {
      float v = Ebuf[tid * 9 + p] * __expf(Pbuf[tid * 9 + p]) + Mbuf[tid * 9 + p];
      Wb[p * 256 + tid] = (__bf16)v;
    }
    __syncthreads();
    __bf16* wb = wt + (size_t)b * 9 * CO * CI + coci0;
#pragma unroll
    for (int i = 0; i < 2; ++i) {
      int s = i * 256 + tid;
      if (s < 288) {
        int p = s >> 5, j = s & 31;
        *(f32x4*)(wb + (size_t)p * CO * CI + j * 8) =
            *(const f32x4*)&Wb[p * 256 + j * 8];
      }
    }
  } else if (bx < 2504) {
    int cid = (bx - 2048) * 256 + tid;
    int pid = cid >> 4;
    int chunk = cid & 15;                    // 16 chunks of 16B per pixel
    int h  = chunk >> 3;                     // ci-half
    int c8 = chunk & 7;
    int b = pid / 228;
    int e = pid - b * 228;
    int ph, pw;
    if (e < 58)       { ph = 0;       pw = e; }
    else if (e < 116) { ph = 57;      pw = e - 58; }
    else if (e < 172) { ph = e - 115; pw = 0; }
    else              { ph = e - 171; pw = 57; }
    f32x4 z = {0.f, 0.f, 0.f, 0.f};
    *(f32x4*)&it[((size_t)(b * 2 + h) * PPIX + ph * PH + pw) * 64 + c8 * 8] = z;
  } else {
    __bf16 (*T)[136] = (__bf16(*)[136])smem;   // [64][136]
    int tx = bx - 2504;
    int b  = tx / 49;
    int p0 = (tx - b * 49) * 64;
    const float* src = in + (size_t)b * CI * NPIX;
#pragma unroll
    for (int jj = 0; jj < 8; ++jj) {
      int c = jj * 256 + tid;
      int ci = c >> 4, xc = c & 15;
      float4 v = *(const float4*)(src + (size_t)ci * NPIX + p0 + xc * 4);
      T[xc * 4 + 0][ci] = (__bf16)v.x;
      T[xc * 4 + 1][ci] = (__bf16)v.y;
      T[xc * 4 + 2][ci] = (__bf16)v.z;
      T[xc * 4 + 3][ci] = (__bf16)v.w;
    }
    __syncthreads();
#pragma unroll
    for (int jj = 0; jj < 4; ++jj) {
      int c = jj * 256 + tid;
      int pl = c >> 4, xc = c & 15;
      int h  = xc >> 3;
      int c8 = xc & 7;
      int pix = p0 + pl;
      int oh = pix / 56, ow = pix - oh * 56;
      int ppix = (oh + 1) * PH + (ow + 1);
      *(f32x4*)&it[((size_t)(b * 2 + h) * PPIX + ppix) * 64 + c8 * 8] =
          *(const f32x4*)&T[pl][xc * 8];
    }
  }
}

// ---------------------------------------------------------------------------
// GEMM/conv with 32x32x16 MFMA: half the MFMA instructions for the same FLOPs.
//   block = 128 co x 224 n (4 image rows), 4 waves by co-group: wave =
//   32 co x 224 n = 7 n-frags of 32 pixels, acc = 7 x f32x16 (112 AGPR).
//   Per step (one tap x 16 ci): 1 A-load (16B/lane), 7 ds_read_b128,
//   7 v_mfma_f32_32x32x16_bf16.  72 steps = 2 ci-halves x 9 taps x 4 kk.
//   Halo per ci-half: 6 padded rows x 58 px x 144B = 50.1KB LDS; restage at
//   midpoint (2 barriers; otherwise barrier-free).  A: dist-2 register ring.
//   B reads left to the compiler (R7 showed hand-pipelining B regresses).
//   A/B frag layout: idx32 = lane&31, k = (lane>>5)*8 + e.  C/D layout
//   (HW-verified m74/m101): col = lane&31, row = (reg&3)+8*(reg>>2)+4*(lane>>5).
//   Grid 14 tiles x 32 b = 448 blocks.
// ---------------------------------------------------------------------------
__global__ __launch_bounds__(256, 2) void bconv_gemm(
    const __bf16* __restrict__ wt,   // [b][9][128 co][128 ci]
    const __bf16* __restrict__ it,   // [b][2 h][3364 px][64 ci]
    float* __restrict__ out) {       // [b][128 co][3136 n]
  __shared__ __align__(16) char Bsh[HPX4 * SROW2];   // 50112 B
  const int tid  = threadIdx.x;
  const int w    = tid >> 6;
  const int lane = tid & 63;
  const int l31  = lane & 31;
  const int hi8  = lane >> 5;

  // Decode: lin = x + 8*(tile*4 + bhi); b = x + 8*bhi -> same-b blocks share an XCD
  const int lin = blockIdx.x;
  const int x   = lin & 7;
  const int j   = lin >> 3;          // 0..55
  const int bhi = j & 3;
  const int tile = j >> 2;           // 0..13
  const int b   = x + 8 * bhi;
  const int oh0 = tile * 4;          // first output row of this tile

  // ---- halo staging, ci-half 0: 348 px x 8 chunks of 16B = 2784 chunks ----
  const __bf16* hsrc0 = it + ((size_t)(b * 2 + 0) * PPIX + oh0 * PH) * 64;
  const __bf16* hsrc1 = it + ((size_t)(b * 2 + 1) * PPIX + oh0 * PH) * 64;
#pragma unroll
  for (int i = 0; i < 11; ++i) {
    int idx = i * 256 + tid;
    if (idx < HPX4 * 8) {
      int px = idx >> 3, sub = idx & 7;
      *(f32x4*)&Bsh[px * SROW2 + sub * 16] = *(const f32x4*)(hsrc0 + (size_t)idx * 8);
    }
  }
  __syncthreads();

  // ---- per-lane B fragment LDS byte-bases (tap (0,0), kk=0) ----
  // frag nf: pixel n = nf*32 + l31 (flat in the 4x56 tile); k = hi8*8 + e
  int bbase[7];
#pragma unroll
  for (int nf = 0; nf < 7; ++nf) {
    int n = nf * 32 + l31;                   // 0..223
    int orow = n / 56;
    int ocol = n - orow * 56;
    bbase[nf] = (orow * PH + ocol) * SROW2 + hi8 * 16;
  }

  // ---- per-lane A global base (elements): co = co0 + l31, k = hi8*8 + e ----
  const int co0 = w * 32;
  const __bf16* wtb = wt + (size_t)b * 9 * CO * CI;
  const int ab = (co0 + l31) * CI + hi8 * 8;

  f32x16 acc[7] = {};
  // distance-2 A-prefetch ring (statically indexed under full unroll)
  // step t: h = t/36, r = t%36, p = r>>2 (tap), kk = r&3 (16-ci chunk)
  // A element offset = p*CO*CI + h*64 + kk*16
  bf16x8 areg[3];
  areg[0] = *(const bf16x8*)(wtb + ab);          // t=0: p0 kk0 h0
  areg[1] = *(const bf16x8*)(wtb + 16 + ab);     // t=1: p0 kk1 h0

#pragma unroll
  for (int s = 0; s < 72; ++s) {
    if (s == 36) {
      __syncthreads();                       // all waves done reading half 0
#pragma unroll
      for (int i = 0; i < 11; ++i) {
        int idx = i * 256 + tid;
        if (idx < HPX4 * 8) {
          int px = idx >> 3, sub = idx & 7;
          *(f32x4*)&Bsh[px * SROW2 + sub * 16] = *(const f32x4*)(hsrc1 + (size_t)idx * 8);
        }
      }
      __syncthreads();
    }
    // prefetch A for step s+2
    if (s < 70) {
      const int tn  = s + 2;
      const int hn  = tn / 36;
      const int rn  = tn % 36;
      const int pn  = rn >> 2;
      const int kkn = rn & 3;
      areg[tn % 3] = *(const bf16x8*)(wtb + pn * (CO * CI) + hn * 64 + kkn * 16 + ab);
    }
    const int r  = s % 36;
    const int p  = r >> 2;
    const int kk = r & 3;
    const int kh = p / 3, kw = p - kh * 3;
    const int tapb = (kh * PH + kw) * SROW2 + kk * 32;   // compile-time (unrolled)
    __builtin_amdgcn_s_setprio(1);
#pragma unroll
    for (int nf = 0; nf < 7; ++nf) {
      bf16x8 bfr = *(const bf16x8*)&Bsh[bbase[nf] + tapb];
      acc[nf] = __builtin_amdgcn_mfma_f32_32x32x16_bf16(areg[s % 3], bfr, acc[nf], 0, 0, 0);
    }
    __builtin_amdgcn_s_setprio(0);
  }

  // ---- epilogue: col(l31)=n, row = (reg&3)+8*(reg>>2)+4*hi8 = co offset ----
  float* ob = out + (size_t)b * CO * NPIX + oh0 * 56;
#pragma unroll
  for (int nf = 0; nf < 7; ++nf) {
#pragma unroll
    for (int rg = 0; rg < 16; ++rg) {
      int co = co0 + (rg & 3) + 8 * (rg >> 2) + 4 * hi8;
      ob[(size_t)co * NPIX + nf * 32 + l31] = acc[nf][rg];
    }
  }
}

// ---------------------------------------------------------------------------
extern "C" void kernel_launch(void* const* d_in, const int* in_sizes, int n_in,
                              void* d_out, int out_size, void* d_ws, size_t ws_size,
                              hipStream_t stream) {
  const float* inp = (const float*)d_in[0];   // [32,128,56,56]
  const float* eps = (const float*)d_in[1];   // [32,128,128,3,3]
  const float* psi = (const float*)d_in[2];   // [128,128,3,3]
  const float* mu  = (const float*)d_in[3];   // [128,128,3,3]

  // ws layout: wt (9,437,184 B) | it (27,557,888 B)
  __bf16* wt = (__bf16*)d_ws;
  __bf16* it = (__bf16*)((char*)d_ws + 9437184);

  prep_all<<<4072, 256, 0, stream>>>(inp, eps, psi, mu, wt, it);
  bconv_gemm<<<448, 256, 0, stream>>>(wt, it, (float*)d_out);
}

// Round 9
// 148.601 us; speedup vs baseline: 1.9217x; 1.0018x over previous
//
#include <hip/hip_runtime.h>
#include <hip/hip_bf16.h>

// Problem constants
#define CO    128
#define CI    128
#define NPIX  3136   // 56*56
#define PH    58
#define PPIX  3364   // 58*58
#define HPX4  348    // halo pixels per 4-row tile: 6 padded rows * 58
#define SROW2 144    // LDS bytes per halo pixel per ci-half: 128 data + 16 pad

typedef __bf16 bf16x8 __attribute__((ext_vector_type(8)));
typedef float  f32x4  __attribute__((ext_vector_type(4)));
typedef float  f32x16 __attribute__((ext_vector_type(16)));

// ---------------------------------------------------------------------------
// Fused prep: [0,2048) weights | [2048,2504) border zero | [2504,4072) transpose.
// it layout: [b][ci-half h][3364 px][64 ci]  (round 3-5 proven version).
// ---------------------------------------------------------------------------
__global__ void prep_all(const float* __restrict__ in,
                         const float* __restrict__ eps,
                         const float* __restrict__ psi,
                         const float* __restrict__ mu,
                         __bf16* __restrict__ wt,
                         __bf16* __restrict__ it) {
  __shared__ __align__(16) char smem[32256];
  const int bx = blockIdx.x, tid = threadIdx.x;

  if (bx < 2048) {
    // ---- weights phase: block covers idx0..idx0+255 (one b, two co) ----
    float* Ebuf = (float*)smem;              // 2304 f32
    float* Pbuf = (float*)(smem + 9216);     // 2304 f32
    float* Mbuf = (float*)(smem + 18432);    // 2304 f32
    __bf16* Wb  = (__bf16*)(smem + 27648);   // [9][256] bf16
    const int idx0  = bx * 256;              // multiple of 256 -> ci0 = 0
    const int b     = idx0 >> 14;            // 64 blocks per b, no straddle
    const int coci0 = idx0 & 16383;          // co0*CI
    const f32x4* esrc = (const f32x4*)(eps + (size_t)idx0 * 9);
    const f32x4* psrc = (const f32x4*)(psi + (size_t)coci0 * 9);
    const f32x4* msrc = (const f32x4*)(mu  + (size_t)coci0 * 9);
#pragma unroll
    for (int i = 0; i < 3; ++i) {            // 576 f32x4 per array
      int j = i * 256 + tid;
      if (j < 576) {
        ((f32x4*)Ebuf)[j] = esrc[j];
        ((f32x4*)Pbuf)[j] = psrc[j];
        ((f32x4*)Mbuf)[j] = msrc[j];
      }
    }
    __syncthreads();
#pragma unroll
    for (int p = 0; p < 9; ++p) {
      float v = Ebuf[tid * 9 + p] * __expf(Pbuf[tid * 9 + p]) + Mbuf[tid * 9 + p];
      Wb[p * 256 + tid] = (__bf16)v;
    }
    __syncthreads();
    __bf16* wb = wt + (size_t)b * 9 * CO * CI + coci0;
#pragma unroll
    for (int i = 0; i < 2; ++i) {
      int s = i * 256 + tid;
      if (s < 288) {
        int p = s >> 5, j = s & 31;
        *(f32x4*)(wb + (size_t)p * CO * CI + j * 8) =
            *(const f32x4*)&Wb[p * 256 + j * 8];
      }
    }
  } else if (bx < 2504) {
    int cid = (bx - 2048) * 256 + tid;
    int pid = cid >> 4;
    int chunk = cid & 15;                    // 16 chunks of 16B per pixel
    int h  = chunk >> 3;                     // ci-half
    int c8 = chunk & 7;
    int b = pid / 228;
    int e = pid - b * 228;
    int ph, pw;
    if (e < 58)       { ph = 0;       pw = e; }
    else if (e < 116) { ph = 57;      pw = e - 58; }
    else if (e < 172) { ph = e - 115; pw = 0; }
    else              { ph = e - 171; pw = 57; }
    f32x4 z = {0.f, 0.f, 0.f, 0.f};
    *(f32x4*)&it[((size_t)(b * 2 + h) * PPIX + ph * PH + pw) * 64 + c8 * 8] = z;
  } else {
    __bf16 (*T)[136] = (__bf16(*)[136])smem;   // [64][136]
    int tx = bx - 2504;
    int b  = tx / 49;
    int p0 = (tx - b * 49) * 64;
    const float* src = in + (size_t)b * CI * NPIX;
#pragma unroll
    for (int jj = 0; jj < 8; ++jj) {
      int c = jj * 256 + tid;
      int ci = c >> 4, xc = c & 15;
      float4 v = *(const float4*)(src + (size_t)ci * NPIX + p0 + xc * 4);
      T[xc * 4 + 0][ci] = (__bf16)v.x;
      T[xc * 4 + 1][ci] = (__bf16)v.y;
      T[xc * 4 + 2][ci] = (__bf16)v.z;
      T[xc * 4 + 3][ci] = (__bf16)v.w;
    }
    __syncthreads();
#pragma unroll
    for (int jj = 0; jj < 4; ++jj) {
      int c = jj * 256 + tid;
      int pl = c >> 4, xc = c & 15;
      int h  = xc >> 3;
      int c8 = xc & 7;
      int pix = p0 + pl;
      int oh = pix / 56, ow = pix - oh * 56;
      int ppix = (oh + 1) * PH + (ow + 1);
      *(f32x4*)&it[((size_t)(b * 2 + h) * PPIX + ppix) * 64 + c8 * 8] =
          *(const f32x4*)&T[pl][xc * 8];
    }
  }
}

// ---------------------------------------------------------------------------
// GEMM/conv, 32x32x16 MFMA with 2 m-frags/wave (B-reuse x2):
//   block = 128 threads (2 waves).  Wave = 64 co x 224 n (2 m-frags x
//   7 n-frags), acc = 14 x f32x16 (224 AGPR, ~300 unified regs -> 1
//   wave/SIMD; 2 blocks/CU fills all 4 SIMDs).  Per step (tap x 16 ci):
//   2 A-loads, 7 ds_read_b128, 14 MFMA — 19.9 KFLOP/instr (R8: 15.3),
//   and per-block B-LDS volume halves vs R8.
//   72 steps = 2 ci-halves x 9 taps x 4 kk; restage at midpoint.
//   Halo per ci-half: 6 padded rows x 58 px x 144B = 50.1KB LDS.
//   A: dist-2 register ring.  B reads left to the compiler (R7 lesson).
//   Grid 14 tiles x 32 b = 448 blocks (<=2/CU, concurrent).
// ---------------------------------------------------------------------------
__global__ __launch_bounds__(128, 1) void bconv_gemm(
    const __bf16* __restrict__ wt,   // [b][9][128 co][128 ci]
    const __bf16* __restrict__ it,   // [b][2 h][3364 px][64 ci]
    float* __restrict__ out) {       // [b][128 co][3136 n]
  __shared__ __align__(16) char Bsh[HPX4 * SROW2];   // 50112 B
  const int tid  = threadIdx.x;
  const int w    = tid >> 6;         // wave 0/1
  const int lane = tid & 63;
  const int l31  = lane & 31;
  const int hi8  = lane >> 5;

  // Decode: lin = x + 8*(tile*4 + bhi); b = x + 8*bhi -> same-b blocks share an XCD
  const int lin = blockIdx.x;
  const int x   = lin & 7;
  const int j   = lin >> 3;          // 0..55
  const int bhi = j & 3;
  const int tile = j >> 2;           // 0..13
  const int b   = x + 8 * bhi;
  const int oh0 = tile * 4;          // first output row of this tile

  // ---- halo staging, ci-half 0: 348 px x 8 chunks of 16B = 2784 chunks ----
  const __bf16* hsrc0 = it + ((size_t)(b * 2 + 0) * PPIX + oh0 * PH) * 64;
  const __bf16* hsrc1 = it + ((size_t)(b * 2 + 1) * PPIX + oh0 * PH) * 64;
#pragma unroll
  for (int i = 0; i < 22; ++i) {
    int idx = i * 128 + tid;
    if (idx < HPX4 * 8) {
      int px = idx >> 3, sub = idx & 7;
      *(f32x4*)&Bsh[px * SROW2 + sub * 16] = *(const f32x4*)(hsrc0 + (size_t)idx * 8);
    }
  }
  __syncthreads();

  // ---- per-lane B fragment LDS byte-bases (tap (0,0), kk=0) ----
  // frag nf: pixel n = nf*32 + l31 (flat in the 4x56 tile); k = hi8*8 + e
  int bbase[7];
#pragma unroll
  for (int nf = 0; nf < 7; ++nf) {
    int n = nf * 32 + l31;                   // 0..223
    int orow = n / 56;
    int ocol = n - orow * 56;
    bbase[nf] = (orow * PH + ocol) * SROW2 + hi8 * 16;
  }

  // ---- per-lane A global bases: co = co0 + mf*32 + l31, k = hi8*8 + e ----
  const int co0 = w * 64;
  const __bf16* wtb = wt + (size_t)b * 9 * CO * CI;
  const int ab0 = (co0 +      l31) * CI + hi8 * 8;
  const int ab1 = (co0 + 32 + l31) * CI + hi8 * 8;

  f32x16 acc[2][7] = {};
  // distance-2 A-prefetch ring (statically indexed under full unroll)
  // step t: h = t/36, r = t%36, p = r>>2 (tap), kk = r&3 (16-ci chunk)
  // A element offset = p*CO*CI + h*64 + kk*16
  bf16x8 areg[3][2];
  areg[0][0] = *(const bf16x8*)(wtb + ab0);        // t=0: p0 kk0 h0
  areg[0][1] = *(const bf16x8*)(wtb + ab1);
  areg[1][0] = *(const bf16x8*)(wtb + 16 + ab0);   // t=1: p0 kk1 h0
  areg[1][1] = *(const bf16x8*)(wtb + 16 + ab1);

#pragma unroll
  for (int s = 0; s < 72; ++s) {
    if (s == 36) {
      __syncthreads();                       // all waves done reading half 0
#pragma unroll
      for (int i = 0; i < 22; ++i) {
        int idx = i * 128 + tid;
        if (idx < HPX4 * 8) {
          int px = idx >> 3, sub = idx & 7;
          *(f32x4*)&Bsh[px * SROW2 + sub * 16] = *(const f32x4*)(hsrc1 + (size_t)idx * 8);
        }
      }
      __syncthreads();
    }
    // prefetch A for step s+2
    if (s < 70) {
      const int tn  = s + 2;
      const int hn  = tn / 36;
      const int rn  = tn % 36;
      const int pn  = rn >> 2;
      const int kkn = rn & 3;
      const __bf16* ap = wtb + pn * (CO * CI) + hn * 64 + kkn * 16;
      areg[tn % 3][0] = *(const bf16x8*)(ap + ab0);
      areg[tn % 3][1] = *(const bf16x8*)(ap + ab1);
    }
    const int r  = s % 36;
    const int p  = r >> 2;
    const int kk = r & 3;
    const int kh = p / 3, kw = p - kh * 3;
    const int tapb = (kh * PH + kw) * SROW2 + kk * 32;   // compile-time (unrolled)
    __builtin_amdgcn_s_setprio(1);
#pragma unroll
    for (int nf = 0; nf < 7; ++nf) {
      bf16x8 bfr = *(const bf16x8*)&Bsh[bbase[nf] + tapb];
      acc[0][nf] = __builtin_amdgcn_mfma_f32_32x32x16_bf16(areg[s % 3][0], bfr, acc[0][nf], 0, 0, 0);
      acc[1][nf] = __builtin_amdgcn_mfma_f32_32x32x16_bf16(areg[s % 3][1], bfr, acc[1][nf], 0, 0, 0);
    }
    __builtin_amdgcn_s_setprio(0);
  }

  // ---- epilogue: col(l31)=n, row = (reg&3)+8*(reg>>2)+4*hi8 = co offset ----
  float* ob = out + (size_t)b * CO * NPIX + oh0 * 56;
#pragma unroll
  for (int mf = 0; mf < 2; ++mf) {
#pragma unroll
    for (int nf = 0; nf < 7; ++nf) {
#pragma unroll
      for (int rg = 0; rg < 16; ++rg) {
        int co = co0 + mf * 32 + (rg & 3) + 8 * (rg >> 2) + 4 * hi8;
        ob[(size_t)co * NPIX + nf * 32 + l31] = acc[mf][nf][rg];
      }
    }
  }
}

// ---------------------------------------------------------------------------
extern "C" void kernel_launch(void* const* d_in, const int* in_sizes, int n_in,
                              void* d_out, int out_size, void* d_ws, size_t ws_size,
                              hipStream_t stream) {
  const float* inp = (const float*)d_in[0];   // [32,128,56,56]
  const float* eps = (const float*)d_in[1];   // [32,128,128,3,3]
  const float* psi = (const float*)d_in[2];   // [128,128,3,3]
  const float* mu  = (const float*)d_in[3];   // [128,128,3,3]

  // ws layout: wt (9,437,184 B) | it (27,557,888 B)
  __bf16* wt = (__bf16*)d_ws;
  __bf16* it = (__bf16*)((char*)d_ws + 9437184);

  prep_all<<<4072, 256, 0, stream>>>(inp, eps, psi, mu, wt, it);
  bconv_gemm<<<448, 128, 0, stream>>>(wt, it, (float*)d_out);
}